// Round 2
// baseline (4392.702 us; speedup 1.0000x reference)
//
#include <hip/hip_runtime.h>

typedef unsigned short u16;
typedef unsigned int u32;
typedef short bf16x8 __attribute__((ext_vector_type(8)));
typedef float floatx4 __attribute__((ext_vector_type(4)));

#define CTX 2048
#define HEADSZ 64
#define NHEAD 16
#define DMODEL 1024
#define DFF 4096
#define MROWS 8192  // B*T

__device__ __forceinline__ u16 f2b(float f) {
  union { float f; u32 i; } x; x.f = f;
  u32 i = x.i;
  return (u16)((i + 0x7fffu + ((i >> 16) & 1u)) >> 16);  // RNE
}
__device__ __forceinline__ u32 pack2(float a, float b) {
  return (u32)f2b(a) | ((u32)f2b(b) << 16);
}
__device__ __forceinline__ void unpack2(u32 u, float& a, float& b) {
  union { u32 i; float f; } x, y;
  x.i = u << 16; y.i = u & 0xffff0000u;
  a = x.f; b = y.f;
}
__device__ __forceinline__ void unpack16(uint4 a, uint4 b, float* d) {
  unpack2(a.x, d[0], d[1]);  unpack2(a.y, d[2], d[3]);
  unpack2(a.z, d[4], d[5]);  unpack2(a.w, d[6], d[7]);
  unpack2(b.x, d[8], d[9]);  unpack2(b.y, d[10], d[11]);
  unpack2(b.z, d[12], d[13]); unpack2(b.w, d[14], d[15]);
}

__device__ __forceinline__ void gl2lds16(const u16* g, u16* l) {
  __builtin_amdgcn_global_load_lds(
      (const __attribute__((address_space(1))) void*)g,
      (__attribute__((address_space(3))) void*)l, 16, 0, 0);
}

// ---------------- elementwise fp32 -> bf16 (4 elems/thread) -------------------
__global__ __launch_bounds__(256) void cvt_f32_bf16(const float* __restrict__ in,
                                                    u16* __restrict__ out) {
  int i = (blockIdx.x * 256 + threadIdx.x) * 4;
  float4 v = *(const float4*)(in + i);
  *(uint2*)(out + i) = make_uint2(pack2(v.x, v.y), pack2(v.z, v.w));
}

// ------------- batched transpose: out_bf16[z][c][r] = in_f32[z][r][c] ---------
__global__ void transpose_f32_bf16(const float* __restrict__ in, u16* __restrict__ out,
                                   int R, int C, long ibs, long obs) {
  __shared__ u16 tile[32][33];
  const float* ip = in + (size_t)blockIdx.z * ibs;
  u16* op = out + (size_t)blockIdx.z * obs;
  int c0 = blockIdx.x * 32, r0 = blockIdx.y * 32;
  int tx = threadIdx.x, ty = threadIdx.y;
#pragma unroll
  for (int i = 0; i < 32; i += 8)
    tile[ty + i][tx] = f2b(ip[(size_t)(r0 + ty + i) * C + (c0 + tx)]);
  __syncthreads();
#pragma unroll
  for (int i = 0; i < 32; i += 8)
    op[(size_t)(c0 + ty + i) * R + (r0 + tx)] = tile[tx][ty + i];
}

// ---------------- GEMM: C[m][n] = sum_k A[m][k] * Bt[n][k]  (+epilogue) --------
// A, Bt are bf16 [.][K].
// MODE 0: scatter bf16 to q/k/v [B,H,T,64] (o0,o1,o2)
// MODE 1: bf16 o0[m*N+n] = acc + bias[n]
// MODE 2: f32  o0[m*N+n] = relu(acc + bias[n])
template <int MODE>
__global__ __launch_bounds__(256) void gemm_bt(
    const u16* __restrict__ A, const u16* __restrict__ Bt,
    const float* __restrict__ bias,
    void* __restrict__ o0v, void* __restrict__ o1v, void* __restrict__ o2v,
    int N, int K) {
  __shared__ __align__(16) u16 As[4 * 128 * 8];
  __shared__ __align__(16) u16 Bs[4 * 128 * 8];
  const int tid = threadIdx.x;
  const int wave = tid >> 6, lane = tid & 63;
  const int quad = lane >> 4, l15 = lane & 15;
  const int wm = wave >> 1, wn = wave & 1;
  const int blockM = blockIdx.y * 128, blockN = blockIdx.x * 128;
  const int rr = tid & 127, kc0 = tid >> 7;

  const u16* ga = A + (size_t)(blockM + rr) * K + kc0 * 8;
  const u16* gb = Bt + (size_t)(blockN + rr) * K + kc0 * 8;
  u16* la0 = As + (size_t)(wave * 64) * 8;
  u16* la1 = As + (size_t)(256 + wave * 64) * 8;
  u16* lb0 = Bs + (size_t)(wave * 64) * 8;
  u16* lb1 = Bs + (size_t)(256 + wave * 64) * 8;

  floatx4 acc[4][4];
#pragma unroll
  for (int i = 0; i < 4; i++)
#pragma unroll
    for (int j = 0; j < 4; j++) acc[i][j] = (floatx4){0.f, 0.f, 0.f, 0.f};

  const int nk = K >> 5;
  for (int kt = 0; kt < nk; kt++) {
    gl2lds16(ga, la0);
    gl2lds16(ga + 16, la1);
    gl2lds16(gb, lb0);
    gl2lds16(gb + 16, lb1);
    ga += 32; gb += 32;
    __syncthreads();
    const bf16x8* Ac = (const bf16x8*)As;
    const bf16x8* Bc = (const bf16x8*)Bs;
    bf16x8 af[4], bfr[4];
#pragma unroll
    for (int i = 0; i < 4; i++) af[i] = Ac[quad * 128 + wm * 64 + i * 16 + l15];
#pragma unroll
    for (int j = 0; j < 4; j++) bfr[j] = Bc[quad * 128 + wn * 64 + j * 16 + l15];
#pragma unroll
    for (int i = 0; i < 4; i++)
#pragma unroll
      for (int j = 0; j < 4; j++)
        acc[i][j] = __builtin_amdgcn_mfma_f32_16x16x32_bf16(af[i], bfr[j], acc[i][j], 0, 0, 0);
    __syncthreads();
  }

  const int m0 = blockM + wm * 64 + quad * 4;
  const int n0 = blockN + wn * 64 + l15;
  if (MODE == 0) {
    u16* o0 = (u16*)o0v; u16* o1 = (u16*)o1v; u16* o2 = (u16*)o2v;
#pragma unroll
    for (int j = 0; j < 4; j++) {
      int n = n0 + j * 16;
      int sec = n >> 10, hh = (n >> 6) & 15, d = n & 63;
      u16* dst = (sec == 0) ? o0 : (sec == 1) ? o1 : o2;
#pragma unroll
      for (int i = 0; i < 4; i++)
#pragma unroll
        for (int r = 0; r < 4; r++) {
          int m = m0 + i * 16 + r;
          int b = m >> 11, t = m & 2047;
          dst[((size_t)((b * 16 + hh) * 2048 + t)) * 64 + d] = f2b(acc[i][j][r]);
        }
    }
  } else if (MODE == 1) {
    u16* o0 = (u16*)o0v;
#pragma unroll
    for (int j = 0; j < 4; j++) {
      int n = n0 + j * 16;
      float bv = bias[n];
#pragma unroll
      for (int i = 0; i < 4; i++)
#pragma unroll
        for (int r = 0; r < 4; r++) {
          int m = m0 + i * 16 + r;
          o0[(size_t)m * N + n] = f2b(acc[i][j][r] + bv);
        }
    }
  } else {
    float* o0 = (float*)o0v;
#pragma unroll
    for (int j = 0; j < 4; j++) {
      int n = n0 + j * 16;
      float bv = bias[n];
#pragma unroll
      for (int i = 0; i < 4; i++)
#pragma unroll
        for (int r = 0; r < 4; r++) {
          int m = m0 + i * 16 + r;
          float v = acc[i][j][r] + bv;
          o0[(size_t)m * N + n] = v > 0.f ? v : 0.f;
        }
    }
  }
}

// ---------------- causal flash attention (vector ALU), bf16 in/out ------------
// q,k,v: [B*H, T, 64] bf16.  out: [B*T, 1024] bf16 (head-concat layout)
__global__ __launch_bounds__(256) void attn_flash(
    const u16* __restrict__ Q, const u16* __restrict__ K,
    const u16* __restrict__ V, u16* __restrict__ out) {
  __shared__ float Kf[64][64];
  __shared__ float Vf[64][64];
  const int tid = threadIdx.x;
  const int bh = blockIdx.y;
  const int t = blockIdx.x * 256 + tid;
  const size_t base = (size_t)bh * CTX * HEADSZ;

  float4 q4[16];
  {
    const uint4* qr = (const uint4*)(Q + base + (size_t)t * HEADSZ);
#pragma unroll
    for (int i = 0; i < 8; i++) {
      uint4 u = qr[i];
      float a, b, c, d, e, f, g, h;
      unpack2(u.x, a, b); unpack2(u.y, c, d);
      unpack2(u.z, e, f); unpack2(u.w, g, h);
      q4[2 * i] = make_float4(a, b, c, d);
      q4[2 * i + 1] = make_float4(e, f, g, h);
    }
  }
  float4 o4[16];
#pragma unroll
  for (int i = 0; i < 16; i++) o4[i] = make_float4(0.f, 0.f, 0.f, 0.f);
  float mmax = -1e30f, l = 0.f;

  const int ntiles = blockIdx.x * 4 + 4;
  const int srow = tid >> 2, scol = (tid & 3) * 16;

  for (int st = 0; st < ntiles; st++) {
    const int s0 = st * 64;
    __syncthreads();
    {
      const u16* kp = K + base + (size_t)(s0 + srow) * HEADSZ + scol;
      const u16* vp = V + base + (size_t)(s0 + srow) * HEADSZ + scol;
      uint4 k0 = ((const uint4*)kp)[0], k1 = ((const uint4*)kp)[1];
      uint4 v0 = ((const uint4*)vp)[0], v1 = ((const uint4*)vp)[1];
      unpack16(k0, k1, &Kf[srow][scol]);
      unpack16(v0, v1, &Vf[srow][scol]);
    }
    __syncthreads();
    int limit = t - s0;
    if (limit >= 0) {
      if (limit > 63) limit = 63;
#pragma unroll 1
      for (int c4 = 0; c4 < 4; c4++) {
        const int sb = c4 * 16;
        if (sb > limit) break;
        float sc[16];
#pragma unroll
        for (int jj = 0; jj < 16; jj++) {
          const float4* kr = (const float4*)(&Kf[sb + jj][0]);
          float a0 = 0.f, a1 = 0.f, a2 = 0.f, a3 = 0.f;
#pragma unroll
          for (int i = 0; i < 16; i += 4) {
            float4 k0 = kr[i], k1 = kr[i + 1], k2 = kr[i + 2], k3 = kr[i + 3];
            a0 += q4[i].x * k0.x + q4[i].y * k0.y + q4[i].z * k0.z + q4[i].w * k0.w;
            a1 += q4[i + 1].x * k1.x + q4[i + 1].y * k1.y + q4[i + 1].z * k1.z + q4[i + 1].w * k1.w;
            a2 += q4[i + 2].x * k2.x + q4[i + 2].y * k2.y + q4[i + 2].z * k2.z + q4[i + 2].w * k2.w;
            a3 += q4[i + 3].x * k3.x + q4[i + 3].y * k3.y + q4[i + 3].z * k3.z + q4[i + 3].w * k3.w;
          }
          float dot = (a0 + a1) + (a2 + a3);
          sc[jj] = (sb + jj <= limit) ? dot * 0.125f : -1e30f;
        }
        float cm = sc[0];
#pragma unroll
        for (int jj = 1; jj < 16; jj++) cm = fmaxf(cm, sc[jj]);
        float mnew = fmaxf(mmax, cm);
        float corr = __expf(mmax - mnew);
        l *= corr;
#pragma unroll
        for (int i = 0; i < 16; i++) {
          o4[i].x *= corr; o4[i].y *= corr; o4[i].z *= corr; o4[i].w *= corr;
        }
#pragma unroll
        for (int jj = 0; jj < 16; jj++) {
          float p = __expf(sc[jj] - mnew);
          l += p;
          const float4* vr = (const float4*)(&Vf[sb + jj][0]);
#pragma unroll
          for (int i = 0; i < 16; i++) {
            o4[i].x += p * vr[i].x; o4[i].y += p * vr[i].y;
            o4[i].z += p * vr[i].z; o4[i].w += p * vr[i].w;
          }
        }
        mmax = mnew;
      }
    }
  }

  const float inv = 1.0f / l;
  u16* orow = out + ((size_t)((bh >> 4) * CTX + t)) * DMODEL + (bh & 15) * HEADSZ;
  uint2* ov = (uint2*)orow;
#pragma unroll
  for (int i = 0; i < 16; i++) {
    float4 v = o4[i];
    ov[i] = make_uint2(pack2(v.x * inv, v.y * inv), pack2(v.z * inv, v.w * inv));
  }
}

extern "C" void kernel_launch(void* const* d_in, const int* in_sizes, int n_in,
                              void* d_out, int out_size, void* d_ws, size_t ws_size,
                              hipStream_t stream) {
  const float* x  = (const float*)d_in[0];
  const float* Wq = (const float*)d_in[1];
  const float* Wk = (const float*)d_in[2];
  const float* Wv = (const float*)d_in[3];
  const float* W1 = (const float*)d_in[4];
  const float* b1 = (const float*)d_in[5];
  const float* W2 = (const float*)d_in[6];
  const float* b2 = (const float*)d_in[7];
  float* out = (float*)d_out;

  // workspace layout (bf16 elements); h reuses the dead xb/Wqkvt/q/k/v region
  u16* ws    = (u16*)d_ws;
  u16* W1t   = ws;                             // [4096][1024]
  u16* W2t   = W1t + (size_t)4096 * 1024;      // [1024][4096]
  u16* att   = W2t + (size_t)4096 * 1024;      // [B*T][1024]
  u16* xb    = att + (size_t)MROWS * 1024;     // [B*T][1024]
  u16* Wqkvt = xb + (size_t)MROWS * 1024;      // [3072][1024]
  u16* q     = Wqkvt + (size_t)3072 * 1024;    // [B*H][T][64]
  u16* k     = q + (size_t)MROWS * 1024;
  u16* v     = k + (size_t)MROWS * 1024;
  u16* h     = xb;                             // [B*T][4096] overlaps xb..v (36.7M >= 33.5M elems)

  // x fp32 -> bf16
  cvt_f32_bf16<<<MROWS * 1024 / 1024, 256, 0, stream>>>(x, xb);

  dim3 tb(32, 8);
  // per-head [1024][64] -> [64][1024] blocks stacked at rows sec*1024 + head*64
  transpose_f32_bf16<<<dim3(2, 32, 16), tb, 0, stream>>>(Wq, Wqkvt,                      1024, 64, 65536, 65536);
  transpose_f32_bf16<<<dim3(2, 32, 16), tb, 0, stream>>>(Wk, Wqkvt + (size_t)1048576,    1024, 64, 65536, 65536);
  transpose_f32_bf16<<<dim3(2, 32, 16), tb, 0, stream>>>(Wv, Wqkvt + (size_t)2097152,    1024, 64, 65536, 65536);
  transpose_f32_bf16<<<dim3(128, 32, 1), tb, 0, stream>>>(W1, W1t, 1024, 4096, 0, 0);
  transpose_f32_bf16<<<dim3(32, 128, 1), tb, 0, stream>>>(W2, W2t, 4096, 1024, 0, 0);

  // QKV projection: [8192][1024] x [3072][1024]^T -> q/k/v scatter
  gemm_bt<0><<<dim3(24, 64), 256, 0, stream>>>(xb, Wqkvt, nullptr, q, k, v, 3072, 1024);
  // causal flash attention -> att [B*T][1024]
  attn_flash<<<dim3(8, 64), 256, 0, stream>>>(q, k, v, att);
  // FFN1: att @ W1 + b1 -> h (bf16)
  gemm_bt<1><<<dim3(32, 64), 256, 0, stream>>>(att, W1t, b1, h, nullptr, nullptr, 4096, 1024);
  // FFN2: relu(h @ W2 + b2) -> out (fp32)
  gemm_bt<2><<<dim3(8, 64), 256, 0, stream>>>(h, W2t, b2, out, nullptr, nullptr, 1024, 4096);
}

// Round 3
// 804.968 us; speedup vs baseline: 5.4570x; 5.4570x over previous
//
#include <hip/hip_runtime.h>
#include <hip/hip_bf16.h>

typedef unsigned short u16;
typedef unsigned int u32;
typedef short bf16x8 __attribute__((ext_vector_type(8)));
typedef float floatx4 __attribute__((ext_vector_type(4)));

#define CTX 2048
#define HEADSZ 64
#define NHEAD 16
#define DMODEL 1024
#define DFF 4096
#define MROWS 8192  // B*T
#define C_SCALE 0.18033688011112042f  // 0.125 * log2(e)

__device__ __forceinline__ u16 f2b(float f) {
  union { float f; u32 i; } x; x.f = f;
  u32 i = x.i;
  return (u16)((i + 0x7fffu + ((i >> 16) & 1u)) >> 16);  // RNE
}
__device__ __forceinline__ u32 pack2(float a, float b) {
  return (u32)f2b(a) | ((u32)f2b(b) << 16);
}
__device__ __forceinline__ floatx4 fmax4(floatx4 a, floatx4 b) {
  floatx4 r;
  r[0] = fmaxf(a[0], b[0]); r[1] = fmaxf(a[1], b[1]);
  r[2] = fmaxf(a[2], b[2]); r[3] = fmaxf(a[3], b[3]);
  return r;
}

__device__ __forceinline__ void gl2lds16(const u16* g, u16* l) {
  __builtin_amdgcn_global_load_lds(
      (const __attribute__((address_space(1))) void*)g,
      (__attribute__((address_space(3))) void*)l, 16, 0, 0);
}

// ---------------- elementwise fp32 -> bf16 (4 elems/thread) -------------------
__global__ __launch_bounds__(256) void cvt_f32_bf16(const float* __restrict__ in,
                                                    u16* __restrict__ out) {
  int i = (blockIdx.x * 256 + threadIdx.x) * 4;
  float4 v = *(const float4*)(in + i);
  *(uint2*)(out + i) = make_uint2(pack2(v.x, v.y), pack2(v.z, v.w));
}

// ------------- batched transpose: out_bf16[z][c][r] = in_f32[z][r][c] ---------
__global__ void transpose_f32_bf16(const float* __restrict__ in, u16* __restrict__ out,
                                   int R, int C, long ibs, long obs) {
  __shared__ u16 tile[32][33];
  const float* ip = in + (size_t)blockIdx.z * ibs;
  u16* op = out + (size_t)blockIdx.z * obs;
  int c0 = blockIdx.x * 32, r0 = blockIdx.y * 32;
  int tx = threadIdx.x, ty = threadIdx.y;
#pragma unroll
  for (int i = 0; i < 32; i += 8)
    tile[ty + i][tx] = f2b(ip[(size_t)(r0 + ty + i) * C + (c0 + tx)]);
  __syncthreads();
#pragma unroll
  for (int i = 0; i < 32; i += 8)
    op[(size_t)(c0 + ty + i) * R + (r0 + tx)] = tile[tx][ty + i];
}

// ---------------- GEMM: C[m][n] = sum_k A[m][k] * Bt[n][k]  (+epilogue) --------
// MODE 0: scatter bf16 to q [B,H,T,64], k [B,H,T,64], vT [B,H,64,T]
// MODE 1: bf16 o0[m*N+n] = acc + bias[n]
// MODE 2: f32  o0[m*N+n] = relu(acc + bias[n])
template <int MODE>
__global__ __launch_bounds__(256) void gemm_bt(
    const u16* __restrict__ A, const u16* __restrict__ Bt,
    const float* __restrict__ bias,
    void* __restrict__ o0v, void* __restrict__ o1v, void* __restrict__ o2v,
    int N, int K) {
  __shared__ __align__(16) u16 As[4 * 128 * 8];
  __shared__ __align__(16) u16 Bs[4 * 128 * 8];
  const int tid = threadIdx.x;
  const int wave = tid >> 6, lane = tid & 63;
  const int quad = lane >> 4, l15 = lane & 15;
  const int wm = wave >> 1, wn = wave & 1;
  const int blockM = blockIdx.y * 128, blockN = blockIdx.x * 128;
  const int rr = tid & 127, kc0 = tid >> 7;

  const u16* ga = A + (size_t)(blockM + rr) * K + kc0 * 8;
  const u16* gb = Bt + (size_t)(blockN + rr) * K + kc0 * 8;
  u16* la0 = As + (size_t)(wave * 64) * 8;
  u16* la1 = As + (size_t)(256 + wave * 64) * 8;
  u16* lb0 = Bs + (size_t)(wave * 64) * 8;
  u16* lb1 = Bs + (size_t)(256 + wave * 64) * 8;

  floatx4 acc[4][4];
#pragma unroll
  for (int i = 0; i < 4; i++)
#pragma unroll
    for (int j = 0; j < 4; j++) acc[i][j] = (floatx4){0.f, 0.f, 0.f, 0.f};

  const int nk = K >> 5;
  for (int kt = 0; kt < nk; kt++) {
    gl2lds16(ga, la0);
    gl2lds16(ga + 16, la1);
    gl2lds16(gb, lb0);
    gl2lds16(gb + 16, lb1);
    ga += 32; gb += 32;
    __syncthreads();
    const bf16x8* Ac = (const bf16x8*)As;
    const bf16x8* Bc = (const bf16x8*)Bs;
    bf16x8 af[4], bfr[4];
#pragma unroll
    for (int i = 0; i < 4; i++) af[i] = Ac[quad * 128 + wm * 64 + i * 16 + l15];
#pragma unroll
    for (int j = 0; j < 4; j++) bfr[j] = Bc[quad * 128 + wn * 64 + j * 16 + l15];
#pragma unroll
    for (int i = 0; i < 4; i++)
#pragma unroll
      for (int j = 0; j < 4; j++)
        acc[i][j] = __builtin_amdgcn_mfma_f32_16x16x32_bf16(af[i], bfr[j], acc[i][j], 0, 0, 0);
    __syncthreads();
  }

  const int m0 = blockM + wm * 64 + quad * 4;
  const int n0 = blockN + wn * 64 + l15;
  if (MODE == 0) {
    u16* o0 = (u16*)o0v; u16* o1 = (u16*)o1v; u16* o2 = (u16*)o2v;
#pragma unroll
    for (int j = 0; j < 4; j++) {
      int n = n0 + j * 16;
      int sec = n >> 10, hh = (n >> 6) & 15, d = n & 63;
      if (sec == 2) {
        // vT[b*16+hh][d][t]
#pragma unroll
        for (int i = 0; i < 4; i++) {
          int t0 = m0 + i * 16;
          int b = t0 >> 11, t = t0 & 2047;
          u16* dst = o2 + ((size_t)((b * 16 + hh) * 64 + d)) * 2048 + t;
          *(u32*)dst = pack2(acc[i][j][0], acc[i][j][1]);
          *(u32*)(dst + 2) = pack2(acc[i][j][2], acc[i][j][3]);
        }
      } else {
        u16* dst = (sec == 0) ? o0 : o1;
#pragma unroll
        for (int i = 0; i < 4; i++)
#pragma unroll
          for (int r = 0; r < 4; r++) {
            int m = m0 + i * 16 + r;
            int b = m >> 11, t = m & 2047;
            dst[((size_t)((b * 16 + hh) * 2048 + t)) * 64 + d] = f2b(acc[i][j][r]);
          }
      }
    }
  } else if (MODE == 1) {
    u16* o0 = (u16*)o0v;
#pragma unroll
    for (int j = 0; j < 4; j++) {
      int n = n0 + j * 16;
      float bv = bias[n];
#pragma unroll
      for (int i = 0; i < 4; i++)
#pragma unroll
        for (int r = 0; r < 4; r++) {
          int m = m0 + i * 16 + r;
          o0[(size_t)m * N + n] = f2b(acc[i][j][r] + bv);
        }
    }
  } else {
    float* o0 = (float*)o0v;
#pragma unroll
    for (int j = 0; j < 4; j++) {
      int n = n0 + j * 16;
      float bv = bias[n];
#pragma unroll
      for (int i = 0; i < 4; i++)
#pragma unroll
        for (int r = 0; r < 4; r++) {
          int m = m0 + i * 16 + r;
          float v = acc[i][j][r] + bv;
          o0[(size_t)m * N + n] = v > 0.f ? v : 0.f;
        }
    }
  }
}

// ---------------- MFMA causal flash attention ---------------------------------
// Q,K: [B*H][T][64] bf16.  Vt: [B*H][64][T] bf16.  out: [B*T][1024] bf16.
// Block = 4 waves; wave w owns 32 q-rows [qt*128+w*32, +32). No __syncthreads.
// St = K·Qt via mfma 16x16x32 (C-layout: lane holds P[m=l15][s=16sc+4q+r]).
// P round-trips wave-private LDS (b64 write / b128 read) to become the B-operand
// of Ot = Vt·Pt (A = vT gathered from global, L2-resident).
__global__ __launch_bounds__(256) void attn_mfma(
    const u16* __restrict__ Q, const u16* __restrict__ K,
    const u16* __restrict__ Vt, u16* __restrict__ out) {
  __shared__ __align__(16) u16 Plds[4][32][72];  // [wave][m][s] pad 72 vs 64
  const int tid = threadIdx.x;
  const int wave = tid >> 6, lane = tid & 63;
  const int quad = lane >> 4, l15 = lane & 15;
  const int bh = blockIdx.y;
  const int u = blockIdx.x;
  const int qt = (u & 1) ? (15 - (u >> 1)) : (u >> 1);  // interleave heavy/light
  const int qbase = qt * 128 + wave * 32;
  const size_t qkb = (size_t)bh * CTX * 64;
  const size_t vb = (size_t)bh * 64 * CTX;

  // Q B-frags (B[k][n=m] layout == row-major row read, same as A)
  bf16x8 qf[2][2];
#pragma unroll
  for (int mt = 0; mt < 2; mt++)
#pragma unroll
    for (int kc = 0; kc < 2; kc++)
      qf[mt][kc] = *(const bf16x8*)(Q + qkb + (size_t)(qbase + mt * 16 + l15) * 64 + kc * 32 + quad * 8);

  floatx4 o[2][4];
#pragma unroll
  for (int mt = 0; mt < 2; mt++)
#pragma unroll
    for (int dt = 0; dt < 4; dt++) o[mt][dt] = (floatx4){0.f, 0.f, 0.f, 0.f};
  float mrow[2] = {-1e30f, -1e30f};
  float lrow[2] = {0.f, 0.f};  // quad-partial; reduced at the end

  const int nst = (qbase + 95) >> 6;  // s-tiles of 64 covering [0, qbase+32)
  for (int st = 0; st < nst; st++) {
    const int sbase = st * 64;
    // St = K·Qt : stf[mt][sc] holds S[q=qbase+16mt+l15][s=sbase+16sc+4q+r]
    floatx4 stf[2][4];
#pragma unroll
    for (int sc = 0; sc < 4; sc++) {
      const u16* kp = K + qkb + (size_t)(sbase + sc * 16 + l15) * 64 + quad * 8;
      bf16x8 k0 = *(const bf16x8*)kp;
      bf16x8 k1 = *(const bf16x8*)(kp + 32);
#pragma unroll
      for (int mt = 0; mt < 2; mt++) {
        floatx4 z = (floatx4){0.f, 0.f, 0.f, 0.f};
        z = __builtin_amdgcn_mfma_f32_16x16x32_bf16(k0, qf[mt][0], z, 0, 0, 0);
        stf[mt][sc] = __builtin_amdgcn_mfma_f32_16x16x32_bf16(k1, qf[mt][1], z, 0, 0, 0);
      }
    }
    // causal mask (only last tile can cross the diagonal)
    if (st == nst - 1) {
#pragma unroll
      for (int mt = 0; mt < 2; mt++) {
        int qq = qbase + mt * 16 + l15;
#pragma unroll
        for (int sc = 0; sc < 4; sc++)
#pragma unroll
          for (int r = 0; r < 4; r++) {
            int s = sbase + sc * 16 + quad * 4 + r;
            if (s > qq) stf[mt][sc][r] = -1e30f;
          }
      }
    }
    // online softmax + pack P^T to wave-private LDS
#pragma unroll
    for (int mt = 0; mt < 2; mt++) {
      floatx4 m4 = fmax4(fmax4(stf[mt][0], stf[mt][1]), fmax4(stf[mt][2], stf[mt][3]));
      float tm = fmaxf(fmaxf(m4[0], m4[1]), fmaxf(m4[2], m4[3]));
      tm = fmaxf(tm, __shfl_xor(tm, 16));
      tm = fmaxf(tm, __shfl_xor(tm, 32));
      float mnew = fmaxf(mrow[mt], tm);
      float alpha = exp2f((mrow[mt] - mnew) * C_SCALE);
      float mc = mnew * C_SCALE;
      mrow[mt] = mnew;
      float lsum = 0.f;
#pragma unroll
      for (int sc = 0; sc < 4; sc++) {
        floatx4 s4 = stf[mt][sc];
        float p0 = exp2f(s4[0] * C_SCALE - mc);
        float p1 = exp2f(s4[1] * C_SCALE - mc);
        float p2 = exp2f(s4[2] * C_SCALE - mc);
        float p3 = exp2f(s4[3] * C_SCALE - mc);
        lsum += (p0 + p1) + (p2 + p3);
        *(uint2*)&Plds[wave][mt * 16 + l15][sc * 16 + quad * 4] =
            make_uint2(pack2(p0, p1), pack2(p2, p3));
      }
      lrow[mt] = lrow[mt] * alpha + lsum;
#pragma unroll
      for (int dt = 0; dt < 4; dt++) o[mt][dt] *= alpha;
    }
    asm volatile("s_waitcnt lgkmcnt(0)" ::: "memory");
    // Ot = Vt · Pt : A = vT[d=16dt+l15][s], B = P[m=l15][s] (same frag layout)
#pragma unroll
    for (int sc2 = 0; sc2 < 2; sc2++) {
      bf16x8 pf[2];
#pragma unroll
      for (int mt = 0; mt < 2; mt++)
        pf[mt] = *(const bf16x8*)&Plds[wave][mt * 16 + l15][sc2 * 32 + quad * 8];
#pragma unroll
      for (int dt = 0; dt < 4; dt++) {
        bf16x8 vf = *(const bf16x8*)(Vt + vb + (size_t)(dt * 16 + l15) * 2048 + sbase + sc2 * 32 + quad * 8);
#pragma unroll
        for (int mt = 0; mt < 2; mt++)
          o[mt][dt] = __builtin_amdgcn_mfma_f32_16x16x32_bf16(vf, pf[mt], o[mt][dt], 0, 0, 0);
      }
    }
  }

  // epilogue: reduce l across quads, normalize, write att (bf16, head-concat)
#pragma unroll
  for (int mt = 0; mt < 2; mt++) {
    float l = lrow[mt];
    l += __shfl_xor(l, 16);
    l += __shfl_xor(l, 32);
    float inv = 1.0f / l;
    int row = (bh >> 4) * CTX + qbase + mt * 16 + l15;
    u16* orow = out + (size_t)row * DMODEL + (bh & 15) * 64;
#pragma unroll
    for (int dt = 0; dt < 4; dt++) {
      floatx4 v = o[mt][dt];
      *(u32*)(orow + dt * 16 + quad * 4) = pack2(v[0] * inv, v[1] * inv);
      *(u32*)(orow + dt * 16 + quad * 4 + 2) = pack2(v[2] * inv, v[3] * inv);
    }
  }
}

extern "C" void kernel_launch(void* const* d_in, const int* in_sizes, int n_in,
                              void* d_out, int out_size, void* d_ws, size_t ws_size,
                              hipStream_t stream) {
  const float* x  = (const float*)d_in[0];
  const float* Wq = (const float*)d_in[1];
  const float* Wk = (const float*)d_in[2];
  const float* Wv = (const float*)d_in[3];
  const float* W1 = (const float*)d_in[4];
  const float* b1 = (const float*)d_in[5];
  const float* W2 = (const float*)d_in[6];
  const float* b2 = (const float*)d_in[7];
  float* out = (float*)d_out;

  // workspace layout (bf16 elements); h reuses the dead xb/Wqkvt/q/k/vt region
  u16* ws    = (u16*)d_ws;
  u16* W1t   = ws;                             // [4096][1024]
  u16* W2t   = W1t + (size_t)4096 * 1024;      // [1024][4096]
  u16* att   = W2t + (size_t)4096 * 1024;      // [B*T][1024]
  u16* xb    = att + (size_t)MROWS * 1024;     // [B*T][1024]
  u16* Wqkvt = xb + (size_t)MROWS * 1024;      // [3072][1024]
  u16* q     = Wqkvt + (size_t)3072 * 1024;    // [B*H][T][64]
  u16* k     = q + (size_t)MROWS * 1024;       // [B*H][T][64]
  u16* vt    = k + (size_t)MROWS * 1024;       // [B*H][64][T]
  u16* h     = xb;                             // [B*T][4096] overlaps xb..vt

  // x fp32 -> bf16
  cvt_f32_bf16<<<MROWS * 1024 / 1024, 256, 0, stream>>>(x, xb);

  dim3 tb(32, 8);
  // per-head [1024][64] -> [64][1024] blocks stacked at rows sec*1024 + head*64
  transpose_f32_bf16<<<dim3(2, 32, 16), tb, 0, stream>>>(Wq, Wqkvt,                   1024, 64, 65536, 65536);
  transpose_f32_bf16<<<dim3(2, 32, 16), tb, 0, stream>>>(Wk, Wqkvt + (size_t)1048576, 1024, 64, 65536, 65536);
  transpose_f32_bf16<<<dim3(2, 32, 16), tb, 0, stream>>>(Wv, Wqkvt + (size_t)2097152, 1024, 64, 65536, 65536);
  transpose_f32_bf16<<<dim3(128, 32, 1), tb, 0, stream>>>(W1, W1t, 1024, 4096, 0, 0);
  transpose_f32_bf16<<<dim3(32, 128, 1), tb, 0, stream>>>(W2, W2t, 4096, 1024, 0, 0);

  // QKV projection: [8192][1024] x [3072][1024]^T -> q/k scatter + vT
  gemm_bt<0><<<dim3(24, 64), 256, 0, stream>>>(xb, Wqkvt, nullptr, q, k, vt, 3072, 1024);
  // MFMA causal flash attention -> att [B*T][1024]
  attn_mfma<<<dim3(16, 64), 256, 0, stream>>>(q, k, vt, att);
  // FFN1: att @ W1 + b1 -> h (bf16)
  gemm_bt<1><<<dim3(32, 64), 256, 0, stream>>>(att, W1t, b1, h, nullptr, nullptr, 4096, 1024);
  // FFN2: relu(h @ W2 + b2) -> out (fp32)
  gemm_bt<2><<<dim3(8, 64), 256, 0, stream>>>(h, W2t, b2, out, nullptr, nullptr, 1024, 4096);
}

// Round 4
// 636.914 us; speedup vs baseline: 6.8969x; 1.2639x over previous
//
#include <hip/hip_runtime.h>
#include <hip/hip_bf16.h>

typedef unsigned short u16;
typedef unsigned int u32;
typedef short bf16x8 __attribute__((ext_vector_type(8)));
typedef float floatx4 __attribute__((ext_vector_type(4)));

#define CTX 2048
#define HEADSZ 64
#define NHEAD 16
#define DMODEL 1024
#define DFF 4096
#define MROWS 8192  // B*T
#define C_SCALE 0.18033688011112042f  // 0.125 * log2(e)

__device__ __forceinline__ u16 f2b(float f) {
  union { float f; u32 i; } x; x.f = f;
  u32 i = x.i;
  return (u16)((i + 0x7fffu + ((i >> 16) & 1u)) >> 16);  // RNE
}
__device__ __forceinline__ u32 pack2(float a, float b) {
  return (u32)f2b(a) | ((u32)f2b(b) << 16);
}
__device__ __forceinline__ floatx4 fmax4(floatx4 a, floatx4 b) {
  floatx4 r;
  r[0] = fmaxf(a[0], b[0]); r[1] = fmaxf(a[1], b[1]);
  r[2] = fmaxf(a[2], b[2]); r[3] = fmaxf(a[3], b[3]);
  return r;
}

__device__ __forceinline__ void gl2lds16(const u16* g, u16* l) {
  __builtin_amdgcn_global_load_lds(
      (const __attribute__((address_space(1))) void*)g,
      (__attribute__((address_space(3))) void*)l, 16, 0, 0);
}

// ---------------- elementwise fp32 -> bf16 (4 elems/thread) -------------------
__global__ __launch_bounds__(256) void cvt_f32_bf16(const float* __restrict__ in,
                                                    u16* __restrict__ out) {
  int i = (blockIdx.x * 256 + threadIdx.x) * 4;
  float4 v = *(const float4*)(in + i);
  *(uint2*)(out + i) = make_uint2(pack2(v.x, v.y), pack2(v.z, v.w));
}

// ------------- batched transpose: out_bf16[z][c][r] = in_f32[z][r][c] ---------
__global__ void transpose_f32_bf16(const float* __restrict__ in, u16* __restrict__ out,
                                   int R, int C, long ibs, long obs) {
  __shared__ u16 tile[32][33];
  const float* ip = in + (size_t)blockIdx.z * ibs;
  u16* op = out + (size_t)blockIdx.z * obs;
  int c0 = blockIdx.x * 32, r0 = blockIdx.y * 32;
  int tx = threadIdx.x, ty = threadIdx.y;
#pragma unroll
  for (int i = 0; i < 32; i += 8)
    tile[ty + i][tx] = f2b(ip[(size_t)(r0 + ty + i) * C + (c0 + tx)]);
  __syncthreads();
#pragma unroll
  for (int i = 0; i < 32; i += 8)
    op[(size_t)(c0 + ty + i) * R + (r0 + tx)] = tile[tx][ty + i];
}

// ------------- bf16 transpose: v [BH][2048][64] -> vt [BH][64][2048] ----------
__global__ void transpose_v_bf16(const u16* __restrict__ in, u16* __restrict__ out) {
  __shared__ u16 tile[32][33];
  const u16* ip = in + (size_t)blockIdx.z * (CTX * 64);
  u16* op = out + (size_t)blockIdx.z * (CTX * 64);
  int c0 = blockIdx.x * 32, r0 = blockIdx.y * 32;
  int tx = threadIdx.x, ty = threadIdx.y;
#pragma unroll
  for (int i = 0; i < 32; i += 8)
    tile[ty + i][tx] = ip[(size_t)(r0 + ty + i) * 64 + (c0 + tx)];
  __syncthreads();
#pragma unroll
  for (int i = 0; i < 32; i += 8)
    op[(size_t)(c0 + ty + i) * CTX + (r0 + tx)] = tile[tx][ty + i];
}

// ---------------- GEMM: C[m][n] = sum_k A[m][k] * Bt[n][k]  (+epilogue) --------
// MODE 0: scatter bf16 to q/k/v [B,H,T,64] (o0,o1,o2)
// MODE 1: bf16 o0[m*N+n] = acc + bias[n]
// MODE 2: f32  o0[m*N+n] = relu(acc + bias[n])
template <int MODE>
__global__ __launch_bounds__(256) void gemm_bt(
    const u16* __restrict__ A, const u16* __restrict__ Bt,
    const float* __restrict__ bias,
    void* __restrict__ o0v, void* __restrict__ o1v, void* __restrict__ o2v,
    int N, int K) {
  __shared__ __align__(16) u16 As[4 * 128 * 8];
  __shared__ __align__(16) u16 Bs[4 * 128 * 8];
  const int tid = threadIdx.x;
  const int wave = tid >> 6, lane = tid & 63;
  const int quad = lane >> 4, l15 = lane & 15;
  const int wm = wave >> 1, wn = wave & 1;
  const int blockM = blockIdx.y * 128, blockN = blockIdx.x * 128;
  const int rr = tid & 127, kc0 = tid >> 7;

  const u16* ga = A + (size_t)(blockM + rr) * K + kc0 * 8;
  const u16* gb = Bt + (size_t)(blockN + rr) * K + kc0 * 8;
  u16* la0 = As + (size_t)(wave * 64) * 8;
  u16* la1 = As + (size_t)(256 + wave * 64) * 8;
  u16* lb0 = Bs + (size_t)(wave * 64) * 8;
  u16* lb1 = Bs + (size_t)(256 + wave * 64) * 8;

  floatx4 acc[4][4];
#pragma unroll
  for (int i = 0; i < 4; i++)
#pragma unroll
    for (int j = 0; j < 4; j++) acc[i][j] = (floatx4){0.f, 0.f, 0.f, 0.f};

  const int nk = K >> 5;
  for (int kt = 0; kt < nk; kt++) {
    gl2lds16(ga, la0);
    gl2lds16(ga + 16, la1);
    gl2lds16(gb, lb0);
    gl2lds16(gb + 16, lb1);
    ga += 32; gb += 32;
    __syncthreads();
    const bf16x8* Ac = (const bf16x8*)As;
    const bf16x8* Bc = (const bf16x8*)Bs;
    bf16x8 af[4], bfr[4];
#pragma unroll
    for (int i = 0; i < 4; i++) af[i] = Ac[quad * 128 + wm * 64 + i * 16 + l15];
#pragma unroll
    for (int j = 0; j < 4; j++) bfr[j] = Bc[quad * 128 + wn * 64 + j * 16 + l15];
#pragma unroll
    for (int i = 0; i < 4; i++)
#pragma unroll
      for (int j = 0; j < 4; j++)
        acc[i][j] = __builtin_amdgcn_mfma_f32_16x16x32_bf16(af[i], bfr[j], acc[i][j], 0, 0, 0);
    __syncthreads();
  }

  const int m0 = blockM + wm * 64 + quad * 4;
  const int n0 = blockN + wn * 64 + l15;
  if (MODE == 0) {
    u16* o0 = (u16*)o0v; u16* o1 = (u16*)o1v; u16* o2 = (u16*)o2v;
#pragma unroll
    for (int j = 0; j < 4; j++) {
      int n = n0 + j * 16;
      int sec = n >> 10, hh = (n >> 6) & 15, d = n & 63;
      u16* dst = (sec == 0) ? o0 : (sec == 1) ? o1 : o2;
#pragma unroll
      for (int i = 0; i < 4; i++)
#pragma unroll
        for (int r = 0; r < 4; r++) {
          int m = m0 + i * 16 + r;
          int b = m >> 11, t = m & 2047;
          dst[((size_t)((b * 16 + hh) * 2048 + t)) * 64 + d] = f2b(acc[i][j][r]);
        }
    }
  } else if (MODE == 1) {
    u16* o0 = (u16*)o0v;
#pragma unroll
    for (int j = 0; j < 4; j++) {
      int n = n0 + j * 16;
      float bv = bias[n];
#pragma unroll
      for (int i = 0; i < 4; i++)
#pragma unroll
        for (int r = 0; r < 4; r++) {
          int m = m0 + i * 16 + r;
          o0[(size_t)m * N + n] = f2b(acc[i][j][r] + bv);
        }
    }
  } else {
    float* o0 = (float*)o0v;
#pragma unroll
    for (int j = 0; j < 4; j++) {
      int n = n0 + j * 16;
      float bv = bias[n];
#pragma unroll
      for (int i = 0; i < 4; i++)
#pragma unroll
        for (int r = 0; r < 4; r++) {
          int m = m0 + i * 16 + r;
          float v = acc[i][j][r] + bv;
          o0[(size_t)m * N + n] = v > 0.f ? v : 0.f;
        }
    }
  }
}

// ---------------- MFMA causal flash attention, LDS-staged, balanced -----------
// Q,K: [B*H][T][64] bf16. Vt: [B*H][64][T] bf16. out: [B*T][1024] bf16.
// Block (4 waves) processes q-tile pair (j, 15-j): uniform 36 stages/block.
// Per stage: K/Vt 64x64 tiles staged to double-buffered LDS via global_load_lds
// (XOR-swizzled cols -> conflict-free ds_read_b128), prefetch of stage st+1
// issued right after the barrier. Wave w owns 32 q-rows of the 128-row tile.
__global__ __launch_bounds__(256) void attn_mfma(
    const u16* __restrict__ Q, const u16* __restrict__ K,
    const u16* __restrict__ Vt, u16* __restrict__ out) {
  __shared__ __align__(16) u16 Kbuf[2][4096];   // [buf][64 s][8 chunks of 8]
  __shared__ __align__(16) u16 Vbuf[2][4096];   // [buf][64 d][8 chunks of 8]
  __shared__ __align__(16) u16 Plds[4][32][72]; // wave-private P
  const int tid = threadIdx.x;
  const int wave = tid >> 6, lane = tid & 63;
  const int quad = lane >> 4, l15 = lane & 15;
  const int sx = l15 & 7;
  const int bh = blockIdx.y;
  const int u = blockIdx.x;
  const size_t qkb = (size_t)bh * CTX * 64;
  const size_t vb = (size_t)bh * 64 * CTX;

  // staging geometry: chunk = (c*4+wave)*64 + lane; LDS[row][col8] holds
  // global col (col8 ^ (row&7)) -> conflict-free b128 frag reads.
  const int ch0 = wave * 64 + lane;
  const int ch1 = 256 + ch0;
  const int r0 = ch0 >> 3, s0 = (ch0 & 7) ^ (r0 & 7);
  const int r1 = ch1 >> 3, s1 = (ch1 & 7) ^ (r1 & 7);
  const u16* kg0 = K + qkb + r0 * 64 + s0 * 8;
  const u16* kg1 = K + qkb + r1 * 64 + s1 * 8;
  const u16* vg0 = Vt + vb + (size_t)r0 * CTX + s0 * 8;
  const u16* vg1 = Vt + vb + (size_t)r1 * CTX + s1 * 8;

#pragma unroll 1
  for (int pass = 0; pass < 2; pass++) {
    const int j = pass ? (15 - u) : u;
    const int qbase = j * 128 + wave * 32;
    const int NST = 2 * j + 2;                  // block-level stage count
    const int nstw = 2 * j + (wave >> 1) + 1;   // this wave computes st < nstw

    // Q B-frags for this q-tile
    bf16x8 qf[2][2];
#pragma unroll
    for (int mt = 0; mt < 2; mt++)
#pragma unroll
      for (int kc = 0; kc < 2; kc++)
        qf[mt][kc] = *(const bf16x8*)(Q + qkb + (size_t)(qbase + mt * 16 + l15) * 64 + kc * 32 + quad * 8);

    floatx4 o[2][4];
#pragma unroll
    for (int mt = 0; mt < 2; mt++)
#pragma unroll
      for (int dt = 0; dt < 4; dt++) o[mt][dt] = (floatx4){0.f, 0.f, 0.f, 0.f};
    float mrow[2] = {-1e30f, -1e30f};
    float lrow[2] = {0.f, 0.f};

    __syncthreads();  // protect buffers from previous pass's readers
    // prologue: stage tile 0 -> buf 0
    gl2lds16(kg0, &Kbuf[0][wave * 512]);
    gl2lds16(kg1, &Kbuf[0][2048 + wave * 512]);
    gl2lds16(vg0, &Vbuf[0][wave * 512]);
    gl2lds16(vg1, &Vbuf[0][2048 + wave * 512]);

#pragma unroll 1
    for (int st = 0; st < NST; st++) {
      __syncthreads();  // buf[st&1] ready; buf[(st+1)&1] free
      if (st + 1 < NST) {
        const int sb = (st + 1) * 64;
        const int b = (st + 1) & 1;
        gl2lds16(kg0 + sb * 64, &Kbuf[b][wave * 512]);
        gl2lds16(kg1 + sb * 64, &Kbuf[b][2048 + wave * 512]);
        gl2lds16(vg0 + sb, &Vbuf[b][wave * 512]);
        gl2lds16(vg1 + sb, &Vbuf[b][2048 + wave * 512]);
      }
      if (st >= nstw) continue;
      const int sbase = st * 64;
      const u16* kb = Kbuf[st & 1];
      const u16* vv = Vbuf[st & 1];

      // St = K·Qt
      floatx4 stf[2][4];
#pragma unroll
      for (int sc = 0; sc < 4; sc++) {
        const bf16x8* kr = (const bf16x8*)(kb + (sc * 16 + l15) * 64);
        bf16x8 k0 = kr[quad ^ sx];
        bf16x8 k1 = kr[(4 + quad) ^ sx];
#pragma unroll
        for (int mt = 0; mt < 2; mt++) {
          floatx4 z = (floatx4){0.f, 0.f, 0.f, 0.f};
          z = __builtin_amdgcn_mfma_f32_16x16x32_bf16(k0, qf[mt][0], z, 0, 0, 0);
          stf[mt][sc] = __builtin_amdgcn_mfma_f32_16x16x32_bf16(k1, qf[mt][1], z, 0, 0, 0);
        }
      }
      // causal mask: only the wave's last stage crosses the diagonal
      if (st == nstw - 1) {
#pragma unroll
        for (int mt = 0; mt < 2; mt++) {
          int qq = qbase + mt * 16 + l15;
#pragma unroll
          for (int sc = 0; sc < 4; sc++)
#pragma unroll
            for (int r = 0; r < 4; r++) {
              int s = sbase + sc * 16 + quad * 4 + r;
              if (s > qq) stf[mt][sc][r] = -1e30f;
            }
        }
      }
      // online softmax + pack P^T to wave-private LDS
#pragma unroll
      for (int mt = 0; mt < 2; mt++) {
        floatx4 m4 = fmax4(fmax4(stf[mt][0], stf[mt][1]), fmax4(stf[mt][2], stf[mt][3]));
        float tm = fmaxf(fmaxf(m4[0], m4[1]), fmaxf(m4[2], m4[3]));
        tm = fmaxf(tm, __shfl_xor(tm, 16));
        tm = fmaxf(tm, __shfl_xor(tm, 32));
        float mnew = fmaxf(mrow[mt], tm);
        float alpha = exp2f((mrow[mt] - mnew) * C_SCALE);
        float mc = mnew * C_SCALE;
        mrow[mt] = mnew;
        float lsum = 0.f;
#pragma unroll
        for (int sc = 0; sc < 4; sc++) {
          floatx4 s4 = stf[mt][sc];
          float p0 = exp2f(s4[0] * C_SCALE - mc);
          float p1 = exp2f(s4[1] * C_SCALE - mc);
          float p2 = exp2f(s4[2] * C_SCALE - mc);
          float p3 = exp2f(s4[3] * C_SCALE - mc);
          lsum += (p0 + p1) + (p2 + p3);
          *(uint2*)&Plds[wave][mt * 16 + l15][sc * 16 + quad * 4] =
              make_uint2(pack2(p0, p1), pack2(p2, p3));
        }
        lrow[mt] = lrow[mt] * alpha + lsum;
#pragma unroll
        for (int dt = 0; dt < 4; dt++) o[mt][dt] *= alpha;
      }
      asm volatile("s_waitcnt lgkmcnt(0)" ::: "memory");
      // Ot += Vt · Pt
#pragma unroll
      for (int sc2 = 0; sc2 < 2; sc2++) {
        bf16x8 pf[2];
#pragma unroll
        for (int mt = 0; mt < 2; mt++)
          pf[mt] = *(const bf16x8*)&Plds[wave][mt * 16 + l15][sc2 * 32 + quad * 8];
#pragma unroll
        for (int dt = 0; dt < 4; dt++) {
          const bf16x8* vr = (const bf16x8*)(vv + (dt * 16 + l15) * 64);
          bf16x8 vf = vr[(sc2 * 4 + quad) ^ sx];
#pragma unroll
          for (int mt = 0; mt < 2; mt++)
            o[mt][dt] = __builtin_amdgcn_mfma_f32_16x16x32_bf16(vf, pf[mt], o[mt][dt], 0, 0, 0);
        }
      }
    }

    // epilogue: reduce l across quads, normalize, write att (bf16, head-concat)
#pragma unroll
    for (int mt = 0; mt < 2; mt++) {
      float l = lrow[mt];
      l += __shfl_xor(l, 16);
      l += __shfl_xor(l, 32);
      float inv = 1.0f / l;
      int row = (bh >> 4) * CTX + qbase + mt * 16 + l15;
      u16* orow = out + (size_t)row * DMODEL + (bh & 15) * 64;
#pragma unroll
      for (int dt = 0; dt < 4; dt++) {
        floatx4 v = o[mt][dt];
        *(u32*)(orow + dt * 16 + quad * 4) = pack2(v[0] * inv, v[1] * inv);
        *(u32*)(orow + dt * 16 + quad * 4 + 2) = pack2(v[2] * inv, v[3] * inv);
      }
    }
  }
}

extern "C" void kernel_launch(void* const* d_in, const int* in_sizes, int n_in,
                              void* d_out, int out_size, void* d_ws, size_t ws_size,
                              hipStream_t stream) {
  const float* x  = (const float*)d_in[0];
  const float* Wq = (const float*)d_in[1];
  const float* Wk = (const float*)d_in[2];
  const float* Wv = (const float*)d_in[3];
  const float* W1 = (const float*)d_in[4];
  const float* b1 = (const float*)d_in[5];
  const float* W2 = (const float*)d_in[6];
  const float* b2 = (const float*)d_in[7];
  float* out = (float*)d_out;

  // workspace (bf16 elems). v lives in att's slot (dead once vt is built);
  // h reuses xb..vt region (vt's tail is dead when FFN1 runs).
  u16* ws    = (u16*)d_ws;
  u16* W1t   = ws;                             // [4096][1024]
  u16* W2t   = W1t + (size_t)4096 * 1024;      // [1024][4096]
  u16* att   = W2t + (size_t)4096 * 1024;      // [B*T][1024]  (also v_tmp)
  u16* xb    = att + (size_t)MROWS * 1024;     // [B*T][1024]
  u16* Wqkvt = xb + (size_t)MROWS * 1024;      // [3072][1024]
  u16* q     = Wqkvt + (size_t)3072 * 1024;    // [B*H][T][64]
  u16* k     = q + (size_t)MROWS * 1024;       // [B*H][T][64]
  u16* vt    = k + (size_t)MROWS * 1024;       // [B*H][64][T]
  u16* v_tmp = att;                            // [B*H][T][64]
  u16* h     = xb;                             // [B*T][4096]

  // x fp32 -> bf16
  cvt_f32_bf16<<<MROWS * 1024 / 1024, 256, 0, stream>>>(x, xb);

  dim3 tb(32, 8);
  // per-head [1024][64] -> [64][1024] blocks stacked at rows sec*1024 + head*64
  transpose_f32_bf16<<<dim3(2, 32, 16), tb, 0, stream>>>(Wq, Wqkvt,                   1024, 64, 65536, 65536);
  transpose_f32_bf16<<<dim3(2, 32, 16), tb, 0, stream>>>(Wk, Wqkvt + (size_t)1048576, 1024, 64, 65536, 65536);
  transpose_f32_bf16<<<dim3(2, 32, 16), tb, 0, stream>>>(Wv, Wqkvt + (size_t)2097152, 1024, 64, 65536, 65536);
  transpose_f32_bf16<<<dim3(128, 32, 1), tb, 0, stream>>>(W1, W1t, 1024, 4096, 0, 0);
  transpose_f32_bf16<<<dim3(32, 128, 1), tb, 0, stream>>>(W2, W2t, 4096, 1024, 0, 0);

  // QKV projection: [8192][1024] x [3072][1024]^T -> q/k/v (coalesced scatter)
  gemm_bt<0><<<dim3(24, 64), 256, 0, stream>>>(xb, Wqkvt, nullptr, q, k, v_tmp, 3072, 1024);
  // v [BH][T][64] -> vt [BH][64][T]
  transpose_v_bf16<<<dim3(2, 64, 64), tb, 0, stream>>>(v_tmp, vt);
  // MFMA causal flash attention -> att [B*T][1024]
  attn_mfma<<<dim3(8, 64), 256, 0, stream>>>(q, k, vt, att);
  // FFN1: att @ W1 + b1 -> h (bf16)
  gemm_bt<1><<<dim3(32, 64), 256, 0, stream>>>(att, W1t, b1, h, nullptr, nullptr, 4096, 1024);
  // FFN2: relu(h @ W2 + b2) -> out (fp32)
  gemm_bt<2><<<dim3(8, 64), 256, 0, stream>>>(h, W2t, b2, out, nullptr, nullptr, 1024, 4096);
}